// Round 1
// baseline (30.332 us; speedup 1.0000x reference)
//
#include <hip/hip_runtime.h>

#define NPATCH 196
#define BATCH  8192
#define TOTAL  (BATCH * NPATCH)

// One thread = one 2x2 patch = one 4-qubit statevector simulation.
// 16 complex amplitudes live entirely in registers; all gate loops are
// fully unrolled so indices are compile-time constants (no scratch).
__global__ __launch_bounds__(256) void quanv_kernel(
    const float* __restrict__ x,   // [B, 784]
    const float* __restrict__ rp,  // [5]
    float4* __restrict__ out)      // [B*196] float4 = [B, 784]
{
    int n = blockIdx.x * 256 + threadIdx.x;
    if (n >= TOTAL) return;
    int b  = n / NPATCH;
    int p  = n - b * NPATCH;
    int pi = p / 14;
    int pj = p - pi * 14;

    const float* img = x + (size_t)b * 784;
    int base = pi * 56 + pj * 2;   // (2*pi)*28 + 2*pj
    float t0 = img[base];
    float t1 = img[base + 1];
    float t2 = img[base + 28];
    float t3 = img[base + 29];

    // Encoder: RY(pixel) on |0> per wire -> (cos(t/2), sin(t/2))
    float s0, c0, s1, c1, s2, c2, s3, c3;
    __sincosf(0.5f * t0, &s0, &c0);
    __sincosf(0.5f * t1, &s1, &c1);
    __sincosf(0.5f * t2, &s2, &c2);
    __sincosf(0.5f * t3, &s3, &c3);

    // Gate parameters (uniform across threads; |p| < ~4pi so half-angle < 2pi,
    // well within __sincosf's accurate range vs the 2% threshold).
    float pA = rp[0], pB = rp[1], pZ = rp[2], pD = rp[3], pG = rp[4];
    float sA, cA, sB, cB, sZ, cZ, sD, cD, sG, cG;
    __sincosf(0.5f * pA, &sA, &cA);  // RX(p0) wire0
    __sincosf(0.5f * pB, &sB, &cB);  // RY(p1) wire1
    __sincosf(0.5f * pZ, &sZ, &cZ);  // RZ(p2) wire2
    __sincosf(0.5f * pD, &sD, &cD);  // RY(p3) wire3
    __sincosf(0.5f * pG, &sG, &cG);  // RX(p4) wire2

    // Build product state: idx = a*8 + b*4 + c*2 + d (wire0 = MSB)
    float re[16], im[16];
    {
        float wa[2] = {c0, s0}, wb[2] = {c1, s1}, wc[2] = {c2, s2}, wd[2] = {c3, s3};
        #pragma unroll
        for (int a = 0; a < 2; ++a)
            #pragma unroll
            for (int bb = 0; bb < 2; ++bb) {
                float ab = wa[a] * wb[bb];
                #pragma unroll
                for (int cc = 0; cc < 2; ++cc)
                    #pragma unroll
                    for (int dd = 0; dd < 2; ++dd) {
                        int idx = a * 8 + bb * 4 + cc * 2 + dd;
                        re[idx] = ab * wc[cc] * wd[dd];
                        im[idx] = 0.0f;
                    }
            }
    }

    // RX pair update: new0 = C*a0 - i*S*a1 ; new1 = -i*S*a0 + C*a1
    #define RXG(I0, I1, C, S) {                                   \
        float r0 = re[I0], q0 = im[I0], r1 = re[I1], q1 = im[I1]; \
        re[I0] = C * r0 + S * q1;  im[I0] = C * q0 - S * r1;      \
        re[I1] = S * q0 + C * r1;  im[I1] = C * q1 - S * r0; }
    // RY pair update (real matrix [[C,-S],[S,C]])
    #define RYG(I0, I1, C, S) {                                   \
        float r0 = re[I0], q0 = im[I0], r1 = re[I1], q1 = im[I1]; \
        re[I0] = C * r0 - S * r1;  im[I0] = C * q0 - S * q1;      \
        re[I1] = S * r0 + C * r1;  im[I1] = S * q0 + C * q1; }
    #define SW(I0, I1) {                                          \
        float tr = re[I0]; re[I0] = re[I1]; re[I1] = tr;          \
        float ti = im[I0]; im[I0] = im[I1]; im[I1] = ti; }

    // 1. RX(p0) on wire0: pairs (k, k+8)
    #pragma unroll
    for (int k = 0; k < 8; ++k) RXG(k, k + 8, cA, sA);

    // 2. RY(p1) on wire1: pairs (k, k+4) where bit2(k)==0
    #pragma unroll
    for (int k = 0; k < 16; ++k) if (!(k & 4)) RYG(k, k + 4, cB, sB);

    // 3. RZ(p2) on wire2: diag(e^{-i p/2}, e^{+i p/2}) on bit1
    #pragma unroll
    for (int i = 0; i < 16; ++i) {
        float r = re[i], q = im[i];
        if (i & 2) { re[i] = cZ * r - sZ * q;  im[i] = cZ * q + sZ * r; }
        else       { re[i] = cZ * r + sZ * q;  im[i] = cZ * q - sZ * r; }
    }

    // 4. CNOT(0,1): a==1 -> flip b
    SW(8, 12) SW(9, 13) SW(10, 14) SW(11, 15)

    // 5. RY(p3) on wire3: pairs (k, k+1), k even
    #pragma unroll
    for (int k = 0; k < 16; k += 2) RYG(k, k + 1, cD, sD);

    // 6. CNOT(2,3): c==1 -> flip d
    SW(2, 3) SW(6, 7) SW(10, 11) SW(14, 15)

    // 7. RX(p4) on wire2: pairs (k, k+2) where bit1(k)==0
    #pragma unroll
    for (int k = 0; k < 16; ++k) if (!(k & 2)) RXG(k, k + 2, cG, sG);

    // 8. CNOT(1,2): b==1 -> flip c
    SW(4, 6) SW(5, 7) SW(12, 14) SW(13, 15)

    // Measure <Z_w>
    float z0 = 0.f, z1 = 0.f, z2 = 0.f, z3 = 0.f;
    #pragma unroll
    for (int i = 0; i < 16; ++i) {
        float pp = re[i] * re[i] + im[i] * im[i];
        z0 += (i & 8) ? -pp : pp;
        z1 += (i & 4) ? -pp : pp;
        z2 += (i & 2) ? -pp : pp;
        z3 += (i & 1) ? -pp : pp;
    }

    out[n] = make_float4(z0, z1, z2, z3);

    #undef RXG
    #undef RYG
    #undef SW
}

extern "C" void kernel_launch(void* const* d_in, const int* in_sizes, int n_in,
                              void* d_out, int out_size, void* d_ws, size_t ws_size,
                              hipStream_t stream) {
    const float* x  = (const float*)d_in[0];
    const float* rp = (const float*)d_in[1];
    float4* out = (float4*)d_out;
    int total = TOTAL;
    int blocks = (total + 255) / 256;
    quanv_kernel<<<blocks, 256, 0, stream>>>(x, rp, out);
}

// Round 2
// 15.390 us; speedup vs baseline: 1.9709x; 1.9709x over previous
//
#include <hip/hip_runtime.h>

#define NPATCH 196
#define BATCH  8192
#define NPAIR  (BATCH * NPATCH / 2)   // one thread handles 2 adjacent patches

// Analytic solution of the 4-qubit circuit (Heisenberg picture):
//   z0 = cos(p0) cos(t0)
//   z1 = cos(p0) cos(t0) cos(t1+p1)
//   z2 = z1 * [cos(p4) cos(t2) + sin(p4) sin(p2) sin(t2) sin(t3+p3)]
//   z3 = cos(t2) cos(t3+p3)
// where (t0,t1,t2,t3) = (top-left, top-right, bottom-left, bottom-right)
// pixels of the 2x2 patch. Exact — no statevector needed.
__global__ __launch_bounds__(256) void quanv_kernel(
    const float* __restrict__ x,   // [B, 784]
    const float* __restrict__ rp,  // [5]
    float4* __restrict__ out)      // [B*196] float4 = [B, 784]
{
    int n2 = blockIdx.x * 256 + threadIdx.x;   // pair index
    if (n2 >= NPAIR) return;

    // n2 -> (image b, patch-row pi, patch-pair pjp); 98 pairs/image, 7 pairs/row
    int b  = n2 / 98;
    int r  = n2 - b * 98;
    int pi = r / 7;
    int pjp = r - pi * 7;

    // top row: 4 consecutive pixels covering patches (pi, 2*pjp) and (pi, 2*pjp+1)
    int base = b * 784 + pi * 56 + pjp * 4;     // 16B-aligned
    float4 top = *(const float4*)(x + base);
    float4 bot = *(const float4*)(x + base + 28);

    // uniform circuit constants (scalar-promoted by compiler)
    float p0 = rp[0], p1 = rp[1], p2 = rp[2], p3 = rp[3], p4 = rp[4];
    float K0  = __cosf(p0);
    float K4  = __cosf(p4);
    float K24 = __sinf(p4) * __sinf(p2);

    float4 o0, o1;
    {
        float ct0 = __cosf(top.x);
        float c1  = __cosf(top.y + p1);
        float st2, ct2; __sincosf(bot.x, &st2, &ct2);
        float s3, c3;   __sincosf(bot.y + p3, &s3, &c3);
        float z0 = K0 * ct0;
        float z1 = z0 * c1;
        float z2 = z1 * (K4 * ct2 + K24 * st2 * s3);
        float z3 = ct2 * c3;
        o0 = make_float4(z0, z1, z2, z3);
    }
    {
        float ct0 = __cosf(top.z);
        float c1  = __cosf(top.w + p1);
        float st2, ct2; __sincosf(bot.z, &st2, &ct2);
        float s3, c3;   __sincosf(bot.w + p3, &s3, &c3);
        float z0 = K0 * ct0;
        float z1 = z0 * c1;
        float z2 = z1 * (K4 * ct2 + K24 * st2 * s3);
        float z3 = ct2 * c3;
        o1 = make_float4(z0, z1, z2, z3);
    }

    out[(size_t)2 * n2]     = o0;
    out[(size_t)2 * n2 + 1] = o1;
}

extern "C" void kernel_launch(void* const* d_in, const int* in_sizes, int n_in,
                              void* d_out, int out_size, void* d_ws, size_t ws_size,
                              hipStream_t stream) {
    const float* x  = (const float*)d_in[0];
    const float* rp = (const float*)d_in[1];
    float4* out = (float4*)d_out;
    int blocks = (NPAIR + 255) / 256;
    quanv_kernel<<<blocks, 256, 0, stream>>>(x, rp, out);
}

// Round 4
// 13.076 us; speedup vs baseline: 2.3198x; 1.1770x over previous
//
#include <hip/hip_runtime.h>

#define NPATCH 196
#define BATCH  8192
#define NPAIR  (BATCH * NPATCH / 2)   // patch pairs (2 adjacent patches each)
#define HALF   (NPAIR / 2)            // each thread does pair u and u+HALF

typedef float f4 __attribute__((ext_vector_type(4)));

// Analytic solution of the 4-qubit circuit (Heisenberg picture):
//   z0 = cos(p0) cos(t0)
//   z1 = cos(p0) cos(t0) cos(t1+p1)
//   z2 = z1 * [cos(p4) cos(t2) + sin(p4) sin(p2) sin(t2) sin(t3+p3)]
//   z3 = cos(t2) cos(t3+p3)
// (t0..t3) = (TL, TR, BL, BR) pixels of the 2x2 patch. Exact.
__global__ __launch_bounds__(256) void quanv_kernel(
    const float* __restrict__ x,   // [B, 784]
    const float* __restrict__ rp,  // [5]
    f4* __restrict__ out)          // [B*196] f4 = [B, 784]
{
    int u = blockIdx.x * 256 + threadIdx.x;
    if (u >= HALF) return;

    // pair index -> load base: 98 pairs/image, 7 pairs per patch-row
    auto base_of = [](int n2) {
        int b   = n2 / 98;
        int r   = n2 - b * 98;
        int pi  = r / 7;
        int pjp = r - pi * 7;
        return b * 784 + pi * 56 + pjp * 4;   // 16B-aligned
    };

    int ba = base_of(u);
    int bb = base_of(u + HALF);

    // Issue all 4 independent 16B loads before any compute (MLP).
    f4 topA = *(const f4*)(x + ba);
    f4 botA = *(const f4*)(x + ba + 28);
    f4 topB = *(const f4*)(x + bb);
    f4 botB = *(const f4*)(x + bb + 28);

    // uniform circuit constants
    float p1 = rp[1], p3 = rp[3];
    float K0  = __cosf(rp[0]);
    float K4  = __cosf(rp[4]);
    float K24 = __sinf(rp[4]) * __sinf(rp[2]);

    #define PATCH(T0, T1, B0, B1, O) {                      \
        float ct0 = __cosf(T0);                             \
        float c1  = __cosf((T1) + p1);                      \
        float st2, ct2; __sincosf((B0), &st2, &ct2);        \
        float s3, c3;   __sincosf((B1) + p3, &s3, &c3);     \
        float z0 = K0 * ct0;                                \
        float z1 = z0 * c1;                                 \
        float z2 = z1 * (K4 * ct2 + K24 * st2 * s3);        \
        float z3 = ct2 * c3;                                \
        O = (f4){z0, z1, z2, z3}; }

    f4 oA0, oA1, oB0, oB1;
    PATCH(topA.x, topA.y, botA.x, botA.y, oA0)
    PATCH(topA.z, topA.w, botA.z, botA.w, oA1)
    PATCH(topB.x, topB.y, botB.x, botB.y, oB0)
    PATCH(topB.z, topB.w, botB.z, botB.w, oB1)
    #undef PATCH

    // write-once output: non-temporal stores skip L2 retention
    __builtin_nontemporal_store(oA0, out + (size_t)2 * u);
    __builtin_nontemporal_store(oA1, out + (size_t)2 * u + 1);
    __builtin_nontemporal_store(oB0, out + (size_t)2 * (u + HALF));
    __builtin_nontemporal_store(oB1, out + (size_t)2 * (u + HALF) + 1);
}

extern "C" void kernel_launch(void* const* d_in, const int* in_sizes, int n_in,
                              void* d_out, int out_size, void* d_ws, size_t ws_size,
                              hipStream_t stream) {
    const float* x  = (const float*)d_in[0];
    const float* rp = (const float*)d_in[1];
    f4* out = (f4*)d_out;
    int blocks = (HALF + 255) / 256;
    quanv_kernel<<<blocks, 256, 0, stream>>>(x, rp, out);
}